// Round 2
// baseline (578.770 us; speedup 1.0000x reference)
//
#include <hip/hip_runtime.h>
#include <hip/hip_cooperative_groups.h>
#include <math.h>

namespace cg = cooperative_groups;

#define B_DIM 4096
#define T_DIM 4096
#define ROWS  4
#define GRID  (B_DIM / ROWS)   // 1024 blocks = 4 blocks/CU * 256 CUs co-resident

constexpr float GAMMA_F = 0.99f;
constexpr float CLIP_V  = 5.0f;

// constexpr-folded gamma powers
constexpr float G2    = GAMMA_F * GAMMA_F; // g^2
constexpr float G4    = G2 * G2;           // g^4
constexpr float G8    = G4 * G4;           // g^8
constexpr float Q1    = G8 * G8;           // g^16
constexpr float Q2    = Q1 * Q1;           // g^32
constexpr float Q4    = Q2 * Q2;           // g^64
constexpr float Q8    = Q4 * Q4;           // g^128
constexpr float Q16   = Q8 * Q8;           // g^256
constexpr float Q32   = Q16 * Q16;         // g^512
constexpr float G1024 = Q32 * Q32;         // g^1024

// g^(4*e), e in [0,63]
__device__ __forceinline__ float pow_g4(int e) {
    float f = 1.0f;
    if (e & 1)  f *= G4;
    if (e & 2)  f *= G8;
    if (e & 4)  f *= Q1;
    if (e & 8)  f *= Q2;
    if (e & 16) f *= Q4;
    if (e & 32) f *= Q8;
    return f;
}

// fast log_sigmoid: arg of log is in [1,2] -> v_log_f32 precision is plenty
__device__ __forceinline__ float lsig(float x) {
    return fminf(x, 0.0f) - __logf(1.0f + __expf(-fabsf(x)));
}

// ---------------------------------------------------------------------------
// Fused cooperative kernel. 1024 blocks x 256 threads, 4 rows/block.
// P0: zero colsum. sync. P1: per-row scan (R1-verified math), write cum,
// adv0 = cum - baselines kept in regs, 4-row-pre-reduced colsum atomics.
// sync. P2: read log_probs only, clip/dot vs in-register adv0, reduce -> obj.
// Eliminates k_colsum's 128MB read + k_obj's 128MB cum/base re-read + all
// inter-kernel drains. __launch_bounds__(256,4): VGPR<=128 -> 4 blk/CU.
// ---------------------------------------------------------------------------
__global__ __launch_bounds__(256, 4) void k_fused(
        const float4* __restrict__ logits, const float4* __restrict__ weight,
        const float4* __restrict__ baselines, const float4* __restrict__ logp,
        float* __restrict__ obj, float4* __restrict__ cum,
        float* __restrict__ colsum) {
    cg::grid_group grid = cg::this_grid();
    __shared__ float waveS[ROWS][4];
    __shared__ float red[ROWS][4];

    const int bid = blockIdx.x, tid = threadIdx.x;
    const int wv = tid >> 6, ln = tid & 63;
    const int seg = wv * 256 + ln;           // float4 index of j=0 granule

    // ---- P0: zero colsum (ws re-poisoned each call) ----
    if (bid < 16) colsum[bid * 256 + tid] = 0.0f;
    __threadfence();                          // release: writeback dirty lines
    grid.sync();

    const float F4[6] = {G4, G8, Q1, Q2, Q4, Q8};   // g^(4*2^k)
    float4 adv[ROWS][4];                      // adv0 = cum - baselines (64 VGPR)

    // ---- P1: scan 4 rows ----
    #pragma unroll
    for (int r = 0; r < ROWS; ++r) {
        const int row = bid * ROWS + r;
        const size_t rb = (size_t)row * (T_DIM / 4);
        float wr[16];
        #pragma unroll
        for (int j = 0; j < 4; ++j) {
            float4 x4 = logits[rb + seg + j * 64];
            float4 w4 = weight[rb + seg + j * 64];
            wr[4 * j + 0] = w4.x * lsig(x4.x);
            wr[4 * j + 1] = w4.y * lsig(x4.y);
            wr[4 * j + 2] = w4.z * lsig(x4.z);
            wr[4 * j + 3] = w4.w * lsig(x4.w);
        }
        float t[4], sn[4];
        #pragma unroll
        for (int j = 0; j < 4; ++j) {
            float V = 0.0f;
            #pragma unroll
            for (int i = 3; i >= 0; --i) V = fmaf(GAMMA_F, V, wr[4 * j + i]);
            float s = V;
            #pragma unroll
            for (int k = 0; k < 6; ++k) {
                int off = 1 << k;
                float u = __shfl_down(s, off, 64);
                if (ln + off < 64) s = fmaf(F4[k], u, s);
            }
            float nx = __shfl_down(s, 1, 64);
            sn[j] = (ln == 63) ? 0.0f : nx;
            t[j]  = __shfl(s, 0, 64);
        }
        float W = fmaf(Q16, fmaf(Q16, fmaf(Q16, t[3], t[2]), t[1]), t[0]);
        if (ln == 0) waveS[r][wv] = W;
        __syncthreads();
        float Anext = 0.0f;
        for (int w2 = 3; w2 > wv; --w2) Anext = fmaf(G1024, Anext, waveS[r][w2]);
        float U[5];
        U[4] = Anext;
        #pragma unroll
        for (int j = 3; j >= 1; --j) U[j] = fmaf(Q16, U[j + 1], t[j]);
        const float fac = pow_g4(63 - ln);
        #pragma unroll
        for (int j = 0; j < 4; ++j) {
            float carry = fmaf(fac, U[j + 1], sn[j]);
            float4 o4;
            o4.w = carry = fmaf(GAMMA_F, carry, wr[4 * j + 3]);
            o4.z = carry = fmaf(GAMMA_F, carry, wr[4 * j + 2]);
            o4.y = carry = fmaf(GAMMA_F, carry, wr[4 * j + 1]);
            o4.x = carry = fmaf(GAMMA_F, carry, wr[4 * j + 0]);
            cum[rb + seg + j * 64] = o4;
            float4 b4 = baselines[rb + seg + j * 64];
            adv[r][j] = make_float4(o4.x - b4.x, o4.y - b4.y,
                                    o4.z - b4.z, o4.w - b4.w);
        }
    }

    // ---- colsum atomics: pre-reduced over the block's 4 rows ----
    #pragma unroll
    for (int j = 0; j < 4; ++j) {
        const int c = 4 * (seg + j * 64);
        atomicAdd(&colsum[c + 0], (adv[0][j].x + adv[1][j].x) + (adv[2][j].x + adv[3][j].x));
        atomicAdd(&colsum[c + 1], (adv[0][j].y + adv[1][j].y) + (adv[2][j].y + adv[3][j].y));
        atomicAdd(&colsum[c + 2], (adv[0][j].z + adv[1][j].z) + (adv[2][j].z + adv[3][j].z));
        atomicAdd(&colsum[c + 3], (adv[0][j].w + adv[1][j].w) + (adv[2][j].w + adv[3][j].w));
    }
    grid.sync();
    __threadfence();                          // acquire: invalidate stale caches

    // ---- P2: objective; only fresh read is log_probs ----
    constexpr float invB = 1.0f / B_DIM;
    float m[4][4];
    #pragma unroll
    for (int j = 0; j < 4; ++j) {
        const int c = 4 * (seg + j * 64);
        #pragma unroll
        for (int i = 0; i < 4; ++i)
            m[j][i] = invB * __hip_atomic_load(&colsum[c + i], __ATOMIC_RELAXED,
                                               __HIP_MEMORY_SCOPE_AGENT);
    }
    float acc[ROWS];
    #pragma unroll
    for (int r = 0; r < ROWS; ++r) {
        const size_t rb = (size_t)(bid * ROWS + r) * (T_DIM / 4);
        float a = 0.0f;
        #pragma unroll
        for (int j = 0; j < 4; ++j) {
            float4 l4 = logp[rb + seg + j * 64];
            float4 v  = adv[r][j];
            float a0 = fminf(fmaxf(v.x - m[j][0], -CLIP_V), CLIP_V);
            float a1 = fminf(fmaxf(v.y - m[j][1], -CLIP_V), CLIP_V);
            float a2 = fminf(fmaxf(v.z - m[j][2], -CLIP_V), CLIP_V);
            float a3 = fminf(fmaxf(v.w - m[j][3], -CLIP_V), CLIP_V);
            a = fmaf(a0, l4.x, a);
            a = fmaf(a1, l4.y, a);
            a = fmaf(a2, l4.z, a);
            a = fmaf(a3, l4.w, a);
        }
        acc[r] = a;
    }
    #pragma unroll
    for (int off = 32; off > 0; off >>= 1) {
        #pragma unroll
        for (int r = 0; r < ROWS; ++r) acc[r] += __shfl_down(acc[r], off, 64);
    }
    if (ln == 0) {
        #pragma unroll
        for (int r = 0; r < ROWS; ++r) red[r][wv] = acc[r];
    }
    __syncthreads();
    if (tid < ROWS)
        obj[bid * ROWS + tid] = (red[tid][0] + red[tid][1]) + (red[tid][2] + red[tid][3]);
}

// ===========================================================================
// Fallback path (R1-verified 4-kernel pipeline), used only if cooperative
// launch is unavailable.
// ===========================================================================
__global__ __launch_bounds__(256) void k_scan(const float4* __restrict__ logits,
                                              const float4* __restrict__ weight,
                                              float4* __restrict__ cum) {
    __shared__ float waveS[4];
    const int row = blockIdx.x;
    const int tid = threadIdx.x;
    const int wv = tid >> 6, ln = tid & 63;
    const size_t rb  = (size_t)row * (T_DIM / 4);
    const int    seg = wv * 256 + ln;

    float wr[16];
    #pragma unroll
    for (int j = 0; j < 4; ++j) {
        float4 x4 = logits[rb + seg + j * 64];
        float4 w4 = weight[rb + seg + j * 64];
        wr[4 * j + 0] = w4.x * lsig(x4.x);
        wr[4 * j + 1] = w4.y * lsig(x4.y);
        wr[4 * j + 2] = w4.z * lsig(x4.z);
        wr[4 * j + 3] = w4.w * lsig(x4.w);
    }
    float t[4], sn[4];
    const float F4[6] = {G4, G8, Q1, Q2, Q4, Q8};
    #pragma unroll
    for (int j = 0; j < 4; ++j) {
        float V = 0.0f;
        #pragma unroll
        for (int i = 3; i >= 0; --i) V = fmaf(GAMMA_F, V, wr[4 * j + i]);
        float s = V;
        #pragma unroll
        for (int k = 0; k < 6; ++k) {
            int off = 1 << k;
            float u = __shfl_down(s, off, 64);
            if (ln + off < 64) s = fmaf(F4[k], u, s);
        }
        float nx = __shfl_down(s, 1, 64);
        sn[j] = (ln == 63) ? 0.0f : nx;
        t[j]  = __shfl(s, 0, 64);
    }
    float W = fmaf(Q16, fmaf(Q16, fmaf(Q16, t[3], t[2]), t[1]), t[0]);
    if (ln == 0) waveS[wv] = W;
    __syncthreads();
    float Anext = 0.0f;
    for (int w2 = 3; w2 > wv; --w2) Anext = fmaf(G1024, Anext, waveS[w2]);
    float U[5];
    U[4] = Anext;
    #pragma unroll
    for (int j = 3; j >= 1; --j) U[j] = fmaf(Q16, U[j + 1], t[j]);
    const float fac = pow_g4(63 - ln);
    #pragma unroll
    for (int j = 0; j < 4; ++j) {
        float carry = fmaf(fac, U[j + 1], sn[j]);
        float4 o4;
        o4.w = carry = fmaf(GAMMA_F, carry, wr[4 * j + 3]);
        o4.z = carry = fmaf(GAMMA_F, carry, wr[4 * j + 2]);
        o4.y = carry = fmaf(GAMMA_F, carry, wr[4 * j + 1]);
        o4.x = carry = fmaf(GAMMA_F, carry, wr[4 * j + 0]);
        cum[rb + seg + j * 64] = o4;
    }
}

__global__ __launch_bounds__(256) void k_zero(float* __restrict__ p) {
    p[blockIdx.x * 256 + threadIdx.x] = 0.0f;
}

__global__ __launch_bounds__(256) void k_colsum(const float* __restrict__ cum,
                                                const float* __restrict__ baselines,
                                                float* __restrict__ colsum) {
    const int t = blockIdx.x * 256 + threadIdx.x;
    size_t p = (size_t)(blockIdx.y * 32) * T_DIM + t;
    float s0 = 0.0f, s1 = 0.0f, s2 = 0.0f, s3 = 0.0f;
    #pragma unroll
    for (int r = 0; r < 32; r += 4) {
        s0 += cum[p] - baselines[p];               p += T_DIM;
        s1 += cum[p] - baselines[p];               p += T_DIM;
        s2 += cum[p] - baselines[p];               p += T_DIM;
        s3 += cum[p] - baselines[p];               p += T_DIM;
    }
    atomicAdd(&colsum[t], (s0 + s1) + (s2 + s3));
}

__global__ __launch_bounds__(256) void k_obj(const float4* __restrict__ cum,
                                             const float4* __restrict__ baselines,
                                             const float4* __restrict__ logp,
                                             const float4* __restrict__ colsum,
                                             float* __restrict__ obj) {
    constexpr float invB = 1.0f / B_DIM;
    const int row = blockIdx.x, tid = threadIdx.x;
    const size_t base4 = (size_t)row * (T_DIM / 4);
    float acc = 0.0f;
    #pragma unroll
    for (int j = 0; j < 4; ++j) {
        int t4 = j * 256 + tid;
        float4 c = cum[base4 + t4];
        float4 b = baselines[base4 + t4];
        float4 l = logp[base4 + t4];
        float4 m = colsum[t4];
        float a0 = fminf(fmaxf(c.x - b.x - m.x * invB, -CLIP_V), CLIP_V);
        float a1 = fminf(fmaxf(c.y - b.y - m.y * invB, -CLIP_V), CLIP_V);
        float a2 = fminf(fmaxf(c.z - b.z - m.z * invB, -CLIP_V), CLIP_V);
        float a3 = fminf(fmaxf(c.w - b.w - m.w * invB, -CLIP_V), CLIP_V);
        acc = fmaf(a0, l.x, acc);
        acc = fmaf(a1, l.y, acc);
        acc = fmaf(a2, l.z, acc);
        acc = fmaf(a3, l.w, acc);
    }
    #pragma unroll
    for (int off = 32; off > 0; off >>= 1) acc += __shfl_down(acc, off, 64);
    __shared__ float ws4[4];
    if ((tid & 63) == 0) ws4[tid >> 6] = acc;
    __syncthreads();
    if (tid == 0) obj[row] = (ws4[0] + ws4[1]) + (ws4[2] + ws4[3]);
}

extern "C" void kernel_launch(void* const* d_in, const int* in_sizes, int n_in,
                              void* d_out, int out_size, void* d_ws, size_t ws_size,
                              hipStream_t stream) {
    const float* log_probs = (const float*)d_in[0];
    const float* logits    = (const float*)d_in[1];
    const float* weight    = (const float*)d_in[2];
    const float* baselines = (const float*)d_in[3];

    float* obj    = (float*)d_out;    // [B]
    float* cum    = obj + B_DIM;      // [B*T]
    float* colsum = (float*)d_ws;     // [T] (16 KB of ws)

    static int coop = -1;
    if (coop < 0) {
        int v = 0;
        hipDeviceGetAttribute(&v, hipDeviceAttributeCooperativeLaunch, 0);
        coop = v;
    }
    if (coop) {
        const float4* lg4 = (const float4*)logits;
        const float4* wt4 = (const float4*)weight;
        const float4* bs4 = (const float4*)baselines;
        const float4* lp4 = (const float4*)log_probs;
        float4*       cm4 = (float4*)cum;
        void* args[] = {(void*)&lg4, (void*)&wt4, (void*)&bs4, (void*)&lp4,
                        (void*)&obj, (void*)&cm4, (void*)&colsum};
        hipError_t rc = hipLaunchCooperativeKernel((const void*)k_fused,
                                                   dim3(GRID), dim3(256),
                                                   args, 0, stream);
        if (rc == hipSuccess) return;
    }

    // fallback: R1 4-kernel pipeline
    k_zero  <<<T_DIM / 256, 256, 0, stream>>>(colsum);
    k_scan  <<<B_DIM, 256, 0, stream>>>((const float4*)logits, (const float4*)weight,
                                        (float4*)cum);
    k_colsum<<<dim3(T_DIM / 256, 128), 256, 0, stream>>>(cum, baselines, colsum);
    k_obj   <<<B_DIM, 256, 0, stream>>>((const float4*)cum, (const float4*)baselines,
                                        (const float4*)log_probs, (const float4*)colsum, obj);
}

// Round 3
// 287.494 us; speedup vs baseline: 2.0132x; 2.0132x over previous
//
#include <hip/hip_runtime.h>
#include <math.h>

#define B_DIM 4096
#define T_DIM 4096
#define ROWS  2
#define NSCAN (B_DIM / ROWS)                 // 2048 scan blocks
#define CG    64                             // groups per colred block

constexpr float GAMMA_F = 0.99f;
constexpr float CLIP_V  = 5.0f;

// constexpr-folded gamma powers
constexpr float G2    = GAMMA_F * GAMMA_F; // g^2
constexpr float G4    = G2 * G2;           // g^4
constexpr float G8    = G4 * G4;           // g^8
constexpr float Q1    = G8 * G8;           // g^16
constexpr float Q2    = Q1 * Q1;           // g^32
constexpr float Q4    = Q2 * Q2;           // g^64
constexpr float Q8    = Q4 * Q4;           // g^128
constexpr float Q16   = Q8 * Q8;           // g^256
constexpr float Q32   = Q16 * Q16;         // g^512
constexpr float G1024 = Q32 * Q32;         // g^1024

// g^(4*e), e in [0,63]
__device__ __forceinline__ float pow_g4(int e) {
    float f = 1.0f;
    if (e & 1)  f *= G4;
    if (e & 2)  f *= G8;
    if (e & 4)  f *= Q1;
    if (e & 8)  f *= Q2;
    if (e & 16) f *= Q4;
    if (e & 32) f *= Q8;
    return f;
}

// fast log_sigmoid: arg of log is in [1,2] -> v_log_f32 precision is plenty
__device__ __forceinline__ float lsig(float x) {
    return fminf(x, 0.0f) - __logf(1.0f + __expf(-fabsf(x)));
}

// ---------------------------------------------------------------------------
// K1 (R3): per-row reverse discounted scan, 2 rows/block SEQUENTIALLY
// (R2 lesson: holding 4 rows of adv live spilled to scratch; sequential rows
// keep peak regs ~ wr[16]+colacc[16]+temps <= ~64 VGPR -> 8 blocks/CU TLP).
// Emits per-block column partials sum_{2 rows}(cum - base) to ws (32 MB,
// no atomics) -> replaces the 128 MB-read k_colsum with a 32 MB k_colred.
// Scan math per row is R1-verified (coalesced lane-stride-16B ownership).
// ---------------------------------------------------------------------------
__global__ __launch_bounds__(256) void k_scan_cs(
        const float4* __restrict__ logits, const float4* __restrict__ weight,
        const float4* __restrict__ baselines, float4* __restrict__ cum,
        float4* __restrict__ partials) {
    __shared__ float waveS[4];
    const int bid = blockIdx.x, tid = threadIdx.x;
    const int wv = tid >> 6, ln = tid & 63;
    const int seg = wv * 256 + ln;           // float4 index of j=0 granule
    const float F4[6] = {G4, G8, Q1, Q2, Q4, Q8};   // g^(4*2^k)

    float4 colacc[4];
    #pragma unroll
    for (int j = 0; j < 4; ++j) colacc[j] = make_float4(0.f, 0.f, 0.f, 0.f);

    #pragma unroll 1
    for (int r = 0; r < ROWS; ++r) {
        const size_t rb = (size_t)(bid * ROWS + r) * (T_DIM / 4);

        float wr[16];
        #pragma unroll
        for (int j = 0; j < 4; ++j) {
            float4 x4 = logits[rb + seg + j * 64];
            float4 w4 = weight[rb + seg + j * 64];
            wr[4 * j + 0] = w4.x * lsig(x4.x);
            wr[4 * j + 1] = w4.y * lsig(x4.y);
            wr[4 * j + 2] = w4.z * lsig(x4.z);
            wr[4 * j + 3] = w4.w * lsig(x4.w);
        }

        float t[4], sn[4];
        #pragma unroll
        for (int j = 0; j < 4; ++j) {
            float V = 0.0f;
            #pragma unroll
            for (int i = 3; i >= 0; --i) V = fmaf(GAMMA_F, V, wr[4 * j + i]);
            float s = V;
            #pragma unroll
            for (int k = 0; k < 6; ++k) {
                int off = 1 << k;
                float u = __shfl_down(s, off, 64);
                if (ln + off < 64) s = fmaf(F4[k], u, s);
            }
            float nx = __shfl_down(s, 1, 64);
            sn[j] = (ln == 63) ? 0.0f : nx;
            t[j]  = __shfl(s, 0, 64);
        }
        float W = fmaf(Q16, fmaf(Q16, fmaf(Q16, t[3], t[2]), t[1]), t[0]);
        if (r) __syncthreads();              // WAR: row0 readers done before overwrite
        if (ln == 0) waveS[wv] = W;
        __syncthreads();
        float Anext = 0.0f;
        for (int w2 = 3; w2 > wv; --w2) Anext = fmaf(G1024, Anext, waveS[w2]);
        float U[5];
        U[4] = Anext;
        #pragma unroll
        for (int j = 3; j >= 1; --j) U[j] = fmaf(Q16, U[j + 1], t[j]);
        const float fac = pow_g4(63 - ln);

        #pragma unroll
        for (int j = 0; j < 4; ++j) {
            float carry = fmaf(fac, U[j + 1], sn[j]);
            float4 o4;
            o4.w = carry = fmaf(GAMMA_F, carry, wr[4 * j + 3]);
            o4.z = carry = fmaf(GAMMA_F, carry, wr[4 * j + 2]);
            o4.y = carry = fmaf(GAMMA_F, carry, wr[4 * j + 1]);
            o4.x = carry = fmaf(GAMMA_F, carry, wr[4 * j + 0]);
            cum[rb + seg + j * 64] = o4;
            float4 b4 = baselines[rb + seg + j * 64];
            colacc[j].x += o4.x - b4.x;
            colacc[j].y += o4.y - b4.y;
            colacc[j].z += o4.z - b4.z;
            colacc[j].w += o4.w - b4.w;
        }
    }

    #pragma unroll
    for (int j = 0; j < 4; ++j)
        partials[(size_t)bid * (T_DIM / 4) + seg + j * 64] = colacc[j];
}

// zero colsum (ws is re-poisoned to 0xAA before every call)
__global__ __launch_bounds__(256) void k_zero(float* __restrict__ p) {
    p[blockIdx.x * 256 + threadIdx.x] = 0.0f;
}

// ---------------------------------------------------------------------------
// K2 (R3): reduce 2048 group-partials -> colsum. grid (16, 2048/CG).
// Coalesced column-major walk; CG rows per block; one atomic per thread.
// ---------------------------------------------------------------------------
__global__ __launch_bounds__(256) void k_colred(const float* __restrict__ partials,
                                                float* __restrict__ colsum) {
    const int col = blockIdx.x * 256 + threadIdx.x;
    size_t p = (size_t)blockIdx.y * CG * T_DIM + col;
    float s0 = 0.0f, s1 = 0.0f, s2 = 0.0f, s3 = 0.0f;
    #pragma unroll 4
    for (int i = 0; i < CG; i += 4) {
        s0 += partials[p];  p += T_DIM;
        s1 += partials[p];  p += T_DIM;
        s2 += partials[p];  p += T_DIM;
        s3 += partials[p];  p += T_DIM;
    }
    atomicAdd(&colsum[col], (s0 + s1) + (s2 + s3));
}

// ---------------------------------------------------------------------------
// K3: obj[row] = sum_t clip(cum - base - colsum/B) * log_probs (unchanged R1)
// ---------------------------------------------------------------------------
__global__ __launch_bounds__(256) void k_obj(const float4* __restrict__ cum,
                                             const float4* __restrict__ baselines,
                                             const float4* __restrict__ logp,
                                             const float4* __restrict__ colsum,
                                             float* __restrict__ obj) {
    constexpr float invB = 1.0f / B_DIM;
    const int row = blockIdx.x, tid = threadIdx.x;
    const size_t base4 = (size_t)row * (T_DIM / 4);
    float acc = 0.0f;
    #pragma unroll
    for (int j = 0; j < 4; ++j) {
        int t4 = j * 256 + tid;
        float4 c = cum[base4 + t4];
        float4 b = baselines[base4 + t4];
        float4 l = logp[base4 + t4];
        float4 m = colsum[t4];
        float a0 = fminf(fmaxf(c.x - b.x - m.x * invB, -CLIP_V), CLIP_V);
        float a1 = fminf(fmaxf(c.y - b.y - m.y * invB, -CLIP_V), CLIP_V);
        float a2 = fminf(fmaxf(c.z - b.z - m.z * invB, -CLIP_V), CLIP_V);
        float a3 = fminf(fmaxf(c.w - b.w - m.w * invB, -CLIP_V), CLIP_V);
        acc = fmaf(a0, l.x, acc);
        acc = fmaf(a1, l.y, acc);
        acc = fmaf(a2, l.z, acc);
        acc = fmaf(a3, l.w, acc);
    }
    #pragma unroll
    for (int off = 32; off > 0; off >>= 1) acc += __shfl_down(acc, off, 64);
    __shared__ float ws4[4];
    if ((tid & 63) == 0) ws4[tid >> 6] = acc;
    __syncthreads();
    if (tid == 0) obj[row] = (ws4[0] + ws4[1]) + (ws4[2] + ws4[3]);
}

// ===========================================================================
// Fallback (R1-verified): 1-row scan + 128MB-read colsum, needs only 16KB ws.
// ===========================================================================
__global__ __launch_bounds__(256) void k_scan(const float4* __restrict__ logits,
                                              const float4* __restrict__ weight,
                                              float4* __restrict__ cum) {
    __shared__ float waveS[4];
    const int row = blockIdx.x;
    const int tid = threadIdx.x;
    const int wv = tid >> 6, ln = tid & 63;
    const size_t rb  = (size_t)row * (T_DIM / 4);
    const int    seg = wv * 256 + ln;

    float wr[16];
    #pragma unroll
    for (int j = 0; j < 4; ++j) {
        float4 x4 = logits[rb + seg + j * 64];
        float4 w4 = weight[rb + seg + j * 64];
        wr[4 * j + 0] = w4.x * lsig(x4.x);
        wr[4 * j + 1] = w4.y * lsig(x4.y);
        wr[4 * j + 2] = w4.z * lsig(x4.z);
        wr[4 * j + 3] = w4.w * lsig(x4.w);
    }
    float t[4], sn[4];
    const float F4[6] = {G4, G8, Q1, Q2, Q4, Q8};
    #pragma unroll
    for (int j = 0; j < 4; ++j) {
        float V = 0.0f;
        #pragma unroll
        for (int i = 3; i >= 0; --i) V = fmaf(GAMMA_F, V, wr[4 * j + i]);
        float s = V;
        #pragma unroll
        for (int k = 0; k < 6; ++k) {
            int off = 1 << k;
            float u = __shfl_down(s, off, 64);
            if (ln + off < 64) s = fmaf(F4[k], u, s);
        }
        float nx = __shfl_down(s, 1, 64);
        sn[j] = (ln == 63) ? 0.0f : nx;
        t[j]  = __shfl(s, 0, 64);
    }
    float W = fmaf(Q16, fmaf(Q16, fmaf(Q16, t[3], t[2]), t[1]), t[0]);
    if (ln == 0) waveS[wv] = W;
    __syncthreads();
    float Anext = 0.0f;
    for (int w2 = 3; w2 > wv; --w2) Anext = fmaf(G1024, Anext, waveS[w2]);
    float U[5];
    U[4] = Anext;
    #pragma unroll
    for (int j = 3; j >= 1; --j) U[j] = fmaf(Q16, U[j + 1], t[j]);
    const float fac = pow_g4(63 - ln);
    #pragma unroll
    for (int j = 0; j < 4; ++j) {
        float carry = fmaf(fac, U[j + 1], sn[j]);
        float4 o4;
        o4.w = carry = fmaf(GAMMA_F, carry, wr[4 * j + 3]);
        o4.z = carry = fmaf(GAMMA_F, carry, wr[4 * j + 2]);
        o4.y = carry = fmaf(GAMMA_F, carry, wr[4 * j + 1]);
        o4.x = carry = fmaf(GAMMA_F, carry, wr[4 * j + 0]);
        cum[rb + seg + j * 64] = o4;
    }
}

__global__ __launch_bounds__(256) void k_colsum(const float* __restrict__ cum,
                                                const float* __restrict__ baselines,
                                                float* __restrict__ colsum) {
    const int t = blockIdx.x * 256 + threadIdx.x;
    size_t p = (size_t)(blockIdx.y * 32) * T_DIM + t;
    float s0 = 0.0f, s1 = 0.0f, s2 = 0.0f, s3 = 0.0f;
    #pragma unroll
    for (int r = 0; r < 32; r += 4) {
        s0 += cum[p] - baselines[p];               p += T_DIM;
        s1 += cum[p] - baselines[p];               p += T_DIM;
        s2 += cum[p] - baselines[p];               p += T_DIM;
        s3 += cum[p] - baselines[p];               p += T_DIM;
    }
    atomicAdd(&colsum[t], (s0 + s1) + (s2 + s3));
}

extern "C" void kernel_launch(void* const* d_in, const int* in_sizes, int n_in,
                              void* d_out, int out_size, void* d_ws, size_t ws_size,
                              hipStream_t stream) {
    const float* log_probs = (const float*)d_in[0];
    const float* logits    = (const float*)d_in[1];
    const float* weight    = (const float*)d_in[2];
    const float* baselines = (const float*)d_in[3];

    float* obj    = (float*)d_out;            // [B]
    float* cum    = obj + B_DIM;              // [B*T]
    float* colsum = (float*)d_ws;             // [T]
    float* partials = colsum + T_DIM;         // [NSCAN*T] = 32 MB

    const size_t need = (size_t)T_DIM * 4 + (size_t)NSCAN * T_DIM * 4;

    if (ws_size >= need) {
        k_zero   <<<T_DIM / 256, 256, 0, stream>>>(colsum);
        k_scan_cs<<<NSCAN, 256, 0, stream>>>((const float4*)logits,
                                             (const float4*)weight,
                                             (const float4*)baselines,
                                             (float4*)cum, (float4*)partials);
        k_colred <<<dim3(T_DIM / 256, NSCAN / CG), 256, 0, stream>>>(partials, colsum);
        k_obj    <<<B_DIM, 256, 0, stream>>>((const float4*)cum,
                                             (const float4*)baselines,
                                             (const float4*)log_probs,
                                             (const float4*)colsum, obj);
    } else {
        // R1-verified fallback (16 KB ws)
        k_zero  <<<T_DIM / 256, 256, 0, stream>>>(colsum);
        k_scan  <<<B_DIM, 256, 0, stream>>>((const float4*)logits,
                                            (const float4*)weight, (float4*)cum);
        k_colsum<<<dim3(T_DIM / 256, 128), 256, 0, stream>>>(cum, baselines, colsum);
        k_obj   <<<B_DIM, 256, 0, stream>>>((const float4*)cum,
                                            (const float4*)baselines,
                                            (const float4*)log_probs,
                                            (const float4*)colsum, obj);
    }
}

// Round 4
// 277.634 us; speedup vs baseline: 2.0846x; 1.0355x over previous
//
#include <hip/hip_runtime.h>
#include <hip/hip_cooperative_groups.h>
#include <math.h>

namespace cg = cooperative_groups;

#define B_DIM 4096
#define T_DIM 4096
#define ROWS  4
#define NBLK  (B_DIM / ROWS)   // 1024 blocks; need 4 blocks/CU co-resident (VGPR<=128)

constexpr float GAMMA_F = 0.99f;
constexpr float CLIP_V  = 5.0f;

// constexpr-folded gamma powers
constexpr float G2    = GAMMA_F * GAMMA_F; // g^2
constexpr float G4    = G2 * G2;           // g^4
constexpr float G8    = G4 * G4;           // g^8
constexpr float Q1    = G8 * G8;           // g^16
constexpr float Q2    = Q1 * Q1;           // g^32
constexpr float Q4    = Q2 * Q2;           // g^64
constexpr float Q8    = Q4 * Q4;           // g^128
constexpr float Q16   = Q8 * Q8;           // g^256
constexpr float Q32   = Q16 * Q16;         // g^512
constexpr float G1024 = Q32 * Q32;         // g^1024

// g^(4*e), e in [0,63]
__device__ __forceinline__ float pow_g4(int e) {
    float f = 1.0f;
    if (e & 1)  f *= G4;
    if (e & 2)  f *= G8;
    if (e & 4)  f *= Q1;
    if (e & 8)  f *= Q2;
    if (e & 16) f *= Q4;
    if (e & 32) f *= Q8;
    return f;
}

// fast log_sigmoid: arg of log is in [1,2] -> v_log_f32 precision is plenty
__device__ __forceinline__ float lsig(float x) {
    return fminf(x, 0.0f) - __logf(1.0f + __expf(-fabsf(x)));
}

// ---------------------------------------------------------------------------
// R4 fused cooperative kernel. 1024 blocks x 256 threads, 4 rows/block.
// R2 lesson (counter-verified): __launch_bounds__(256,4) forced VGPR=64 and
// spilled ~88MB to scratch. Here: NO min-waves bound (allocator free to use
// ~110 VGPR; 4 blk/CU needs only <=128), per-row NAMED register arrays with
// block-uniform branches (no runtime-indexed array -> no scratch), partials
// in ws instead of 8M atomics. adv (=cum-baselines) stays in registers
// across both grid syncs, so P2b reads ONLY log_probs.
// Traffic: 192R+80W (P1) + 16R (P2a) + 64R (P2b) = 352 MB, one dispatch.
// ---------------------------------------------------------------------------
__global__ __launch_bounds__(256) void k_fused(
        const float4* __restrict__ logits, const float4* __restrict__ weight,
        const float4* __restrict__ baselines, const float4* __restrict__ logp,
        float* __restrict__ obj, float4* __restrict__ cum,
        float4* __restrict__ partials, float* __restrict__ colsum) {
    cg::grid_group grid = cg::this_grid();
    __shared__ float waveS[4];
    __shared__ float red[ROWS][4];

    const int bid = blockIdx.x, tid = threadIdx.x;
    const int wv = tid >> 6, ln = tid & 63;
    const int seg = wv * 256 + ln;            // float4 index of j=0 granule
    const float F4[6] = {G4, G8, Q1, Q2, Q4, Q8};   // g^(4*2^k)
    const float fac = pow_g4(63 - ln);        // row-independent: hoisted

    // zero colsum before sync1 (atomics target in P2a)
    if (bid < 16) colsum[bid * 256 + tid] = 0.0f;

    // per-row adv registers: NAMED arrays, statically indexed everywhere
    float4 a0[4], a1[4], a2[4], a3[4];

    // ---- P1: scan ROWS rows sequentially (unroll 1 keeps peak pressure low)
    #pragma unroll 1
    for (int r = 0; r < ROWS; ++r) {
        const size_t rb = (size_t)(bid * ROWS + r) * (T_DIM / 4);

        float wr[16];
        #pragma unroll
        for (int j = 0; j < 4; ++j) {
            float4 x4 = logits[rb + seg + j * 64];
            float4 w4 = weight[rb + seg + j * 64];
            wr[4 * j + 0] = w4.x * lsig(x4.x);
            wr[4 * j + 1] = w4.y * lsig(x4.y);
            wr[4 * j + 2] = w4.z * lsig(x4.z);
            wr[4 * j + 3] = w4.w * lsig(x4.w);
        }

        float t[4], sn[4];
        #pragma unroll
        for (int j = 0; j < 4; ++j) {
            float V = 0.0f;
            #pragma unroll
            for (int i = 3; i >= 0; --i) V = fmaf(GAMMA_F, V, wr[4 * j + i]);
            float s = V;
            #pragma unroll
            for (int k = 0; k < 6; ++k) {
                int off = 1 << k;
                float u = __shfl_down(s, off, 64);
                if (ln + off < 64) s = fmaf(F4[k], u, s);
            }
            float nx = __shfl_down(s, 1, 64);
            sn[j] = (ln == 63) ? 0.0f : nx;
            t[j]  = __shfl(s, 0, 64);
        }
        float W = fmaf(Q16, fmaf(Q16, fmaf(Q16, t[3], t[2]), t[1]), t[0]);
        if (r) __syncthreads();               // WAR on waveS
        if (ln == 0) waveS[wv] = W;
        __syncthreads();
        float Anext = 0.0f;
        for (int w2 = 3; w2 > wv; --w2) Anext = fmaf(G1024, Anext, waveS[w2]);
        float U[5];
        U[4] = Anext;
        #pragma unroll
        for (int j = 3; j >= 1; --j) U[j] = fmaf(Q16, U[j + 1], t[j]);

        #pragma unroll
        for (int j = 0; j < 4; ++j) {
            float carry = fmaf(fac, U[j + 1], sn[j]);
            float4 o4;
            o4.w = carry = fmaf(GAMMA_F, carry, wr[4 * j + 3]);
            o4.z = carry = fmaf(GAMMA_F, carry, wr[4 * j + 2]);
            o4.y = carry = fmaf(GAMMA_F, carry, wr[4 * j + 1]);
            o4.x = carry = fmaf(GAMMA_F, carry, wr[4 * j + 0]);
            cum[rb + seg + j * 64] = o4;
            float4 b4 = baselines[rb + seg + j * 64];
            float4 av = make_float4(o4.x - b4.x, o4.y - b4.y,
                                    o4.z - b4.z, o4.w - b4.w);
            if      (r == 0) a0[j] = av;      // uniform branch, static index
            else if (r == 1) a1[j] = av;
            else if (r == 2) a2[j] = av;
            else             a3[j] = av;
        }
    }

    // per-block column partials, pre-reduced over the 4 rows
    #pragma unroll
    for (int j = 0; j < 4; ++j) {
        float4 s;
        s.x = (a0[j].x + a1[j].x) + (a2[j].x + a3[j].x);
        s.y = (a0[j].y + a1[j].y) + (a2[j].y + a3[j].y);
        s.z = (a0[j].z + a1[j].z) + (a2[j].z + a3[j].z);
        s.w = (a0[j].w + a1[j].w) + (a2[j].w + a3[j].w);
        partials[(size_t)bid * (T_DIM / 4) + seg + j * 64] = s;
    }
    __threadfence();
    grid.sync();
    __threadfence();

    // ---- P2a: reduce partials [NBLK][T] -> colsum. 16 colgroups x 64 rowgrps
    {
        const int cgp = bid & 15, rg = bid >> 4;
        const int col = cgp * 256 + tid;
        const float* P = (const float*)partials;
        size_t p = (size_t)(rg * 16) * T_DIM + col;
        float s0 = 0.f, s1 = 0.f, s2 = 0.f, s3 = 0.f;
        #pragma unroll
        for (int i = 0; i < 16; i += 4) {
            s0 += P[p];  p += T_DIM;
            s1 += P[p];  p += T_DIM;
            s2 += P[p];  p += T_DIM;
            s3 += P[p];  p += T_DIM;
        }
        atomicAdd(&colsum[col], (s0 + s1) + (s2 + s3));
    }
    __threadfence();
    grid.sync();
    __threadfence();

    // ---- P2b: objective; only fresh HBM read is log_probs ----
    constexpr float invB = 1.0f / B_DIM;
    float4 m[4];
    #pragma unroll
    for (int j = 0; j < 4; ++j) {
        const int c = 4 * (seg + j * 64);
        m[j].x = invB * __hip_atomic_load(&colsum[c + 0], __ATOMIC_RELAXED,
                                          __HIP_MEMORY_SCOPE_AGENT);
        m[j].y = invB * __hip_atomic_load(&colsum[c + 1], __ATOMIC_RELAXED,
                                          __HIP_MEMORY_SCOPE_AGENT);
        m[j].z = invB * __hip_atomic_load(&colsum[c + 2], __ATOMIC_RELAXED,
                                          __HIP_MEMORY_SCOPE_AGENT);
        m[j].w = invB * __hip_atomic_load(&colsum[c + 3], __ATOMIC_RELAXED,
                                          __HIP_MEMORY_SCOPE_AGENT);
    }
    float acc[ROWS];
    #define ROW_DOT(R, AR)                                                    \
    {                                                                         \
        const size_t rb = (size_t)(bid * ROWS + (R)) * (T_DIM / 4);           \
        float a = 0.0f;                                                       \
        _Pragma("unroll")                                                     \
        for (int j = 0; j < 4; ++j) {                                         \
            float4 l4 = logp[rb + seg + j * 64];                              \
            float q0 = fminf(fmaxf(AR[j].x - m[j].x, -CLIP_V), CLIP_V);       \
            float q1 = fminf(fmaxf(AR[j].y - m[j].y, -CLIP_V), CLIP_V);       \
            float q2 = fminf(fmaxf(AR[j].z - m[j].z, -CLIP_V), CLIP_V);       \
            float q3 = fminf(fmaxf(AR[j].w - m[j].w, -CLIP_V), CLIP_V);       \
            a = fmaf(q0, l4.x, a);                                            \
            a = fmaf(q1, l4.y, a);                                            \
            a = fmaf(q2, l4.z, a);                                            \
            a = fmaf(q3, l4.w, a);                                            \
        }                                                                     \
        acc[R] = a;                                                           \
    }
    ROW_DOT(0, a0)
    ROW_DOT(1, a1)
    ROW_DOT(2, a2)
    ROW_DOT(3, a3)
    #undef ROW_DOT

    #pragma unroll
    for (int off = 32; off > 0; off >>= 1) {
        #pragma unroll
        for (int r = 0; r < ROWS; ++r) acc[r] += __shfl_down(acc[r], off, 64);
    }
    if (ln == 0) {
        #pragma unroll
        for (int r = 0; r < ROWS; ++r) red[r][wv] = acc[r];
    }
    __syncthreads();
    if (tid < ROWS)
        obj[bid * ROWS + tid] = (red[tid][0] + red[tid][1]) + (red[tid][2] + red[tid][3]);
}

// ===========================================================================
// Fallback (R1-verified 4-kernel pipeline, 281 us) — used if the cooperative
// co-residency check fails (e.g. VGPR > 128 -> <4 blocks/CU).
// ===========================================================================
__global__ __launch_bounds__(256) void k_zero(float* __restrict__ p) {
    p[blockIdx.x * 256 + threadIdx.x] = 0.0f;
}

__global__ __launch_bounds__(256) void k_scan(const float4* __restrict__ logits,
                                              const float4* __restrict__ weight,
                                              float4* __restrict__ cum) {
    __shared__ float waveS[4];
    const int row = blockIdx.x;
    const int tid = threadIdx.x;
    const int wv = tid >> 6, ln = tid & 63;
    const size_t rb  = (size_t)row * (T_DIM / 4);
    const int    seg = wv * 256 + ln;

    float wr[16];
    #pragma unroll
    for (int j = 0; j < 4; ++j) {
        float4 x4 = logits[rb + seg + j * 64];
        float4 w4 = weight[rb + seg + j * 64];
        wr[4 * j + 0] = w4.x * lsig(x4.x);
        wr[4 * j + 1] = w4.y * lsig(x4.y);
        wr[4 * j + 2] = w4.z * lsig(x4.z);
        wr[4 * j + 3] = w4.w * lsig(x4.w);
    }
    float t[4], sn[4];
    const float F4[6] = {G4, G8, Q1, Q2, Q4, Q8};
    #pragma unroll
    for (int j = 0; j < 4; ++j) {
        float V = 0.0f;
        #pragma unroll
        for (int i = 3; i >= 0; --i) V = fmaf(GAMMA_F, V, wr[4 * j + i]);
        float s = V;
        #pragma unroll
        for (int k = 0; k < 6; ++k) {
            int off = 1 << k;
            float u = __shfl_down(s, off, 64);
            if (ln + off < 64) s = fmaf(F4[k], u, s);
        }
        float nx = __shfl_down(s, 1, 64);
        sn[j] = (ln == 63) ? 0.0f : nx;
        t[j]  = __shfl(s, 0, 64);
    }
    float W = fmaf(Q16, fmaf(Q16, fmaf(Q16, t[3], t[2]), t[1]), t[0]);
    if (ln == 0) waveS[wv] = W;
    __syncthreads();
    float Anext = 0.0f;
    for (int w2 = 3; w2 > wv; --w2) Anext = fmaf(G1024, Anext, waveS[w2]);
    float U[5];
    U[4] = Anext;
    #pragma unroll
    for (int j = 3; j >= 1; --j) U[j] = fmaf(Q16, U[j + 1], t[j]);
    const float fac = pow_g4(63 - ln);
    #pragma unroll
    for (int j = 0; j < 4; ++j) {
        float carry = fmaf(fac, U[j + 1], sn[j]);
        float4 o4;
        o4.w = carry = fmaf(GAMMA_F, carry, wr[4 * j + 3]);
        o4.z = carry = fmaf(GAMMA_F, carry, wr[4 * j + 2]);
        o4.y = carry = fmaf(GAMMA_F, carry, wr[4 * j + 1]);
        o4.x = carry = fmaf(GAMMA_F, carry, wr[4 * j + 0]);
        cum[rb + seg + j * 64] = o4;
    }
}

__global__ __launch_bounds__(256) void k_colsum(const float* __restrict__ cum,
                                                const float* __restrict__ baselines,
                                                float* __restrict__ colsum) {
    const int t = blockIdx.x * 256 + threadIdx.x;
    size_t p = (size_t)(blockIdx.y * 32) * T_DIM + t;
    float s0 = 0.0f, s1 = 0.0f, s2 = 0.0f, s3 = 0.0f;
    #pragma unroll
    for (int r = 0; r < 32; r += 4) {
        s0 += cum[p] - baselines[p];               p += T_DIM;
        s1 += cum[p] - baselines[p];               p += T_DIM;
        s2 += cum[p] - baselines[p];               p += T_DIM;
        s3 += cum[p] - baselines[p];               p += T_DIM;
    }
    atomicAdd(&colsum[t], (s0 + s1) + (s2 + s3));
}

__global__ __launch_bounds__(256) void k_obj(const float4* __restrict__ cum,
                                             const float4* __restrict__ baselines,
                                             const float4* __restrict__ logp,
                                             const float4* __restrict__ colsum,
                                             float* __restrict__ obj) {
    constexpr float invB = 1.0f / B_DIM;
    const int row = blockIdx.x, tid = threadIdx.x;
    const size_t base4 = (size_t)row * (T_DIM / 4);
    float acc = 0.0f;
    #pragma unroll
    for (int j = 0; j < 4; ++j) {
        int t4 = j * 256 + tid;
        float4 c = cum[base4 + t4];
        float4 b = baselines[base4 + t4];
        float4 l = logp[base4 + t4];
        float4 m = colsum[t4];
        float a0 = fminf(fmaxf(c.x - b.x - m.x * invB, -CLIP_V), CLIP_V);
        float a1 = fminf(fmaxf(c.y - b.y - m.y * invB, -CLIP_V), CLIP_V);
        float a2 = fminf(fmaxf(c.z - b.z - m.z * invB, -CLIP_V), CLIP_V);
        float a3 = fminf(fmaxf(c.w - b.w - m.w * invB, -CLIP_V), CLIP_V);
        acc = fmaf(a0, l.x, acc);
        acc = fmaf(a1, l.y, acc);
        acc = fmaf(a2, l.z, acc);
        acc = fmaf(a3, l.w, acc);
    }
    #pragma unroll
    for (int off = 32; off > 0; off >>= 1) acc += __shfl_down(acc, off, 64);
    __shared__ float ws4[4];
    if ((tid & 63) == 0) ws4[tid >> 6] = acc;
    __syncthreads();
    if (tid == 0) obj[row] = (ws4[0] + ws4[1]) + (ws4[2] + ws4[3]);
}

extern "C" void kernel_launch(void* const* d_in, const int* in_sizes, int n_in,
                              void* d_out, int out_size, void* d_ws, size_t ws_size,
                              hipStream_t stream) {
    const float* log_probs = (const float*)d_in[0];
    const float* logits    = (const float*)d_in[1];
    const float* weight    = (const float*)d_in[2];
    const float* baselines = (const float*)d_in[3];

    float* obj      = (float*)d_out;          // [B]
    float* cum      = obj + B_DIM;            // [B*T]
    float* colsum   = (float*)d_ws;           // [T]
    float* partials = colsum + T_DIM;         // [NBLK*T] = 16 MB

    const size_t need = (size_t)T_DIM * 4 + (size_t)NBLK * T_DIM * 4;

    static int coop_ok = -1;
    if (coop_ok < 0) {
        int coop = 0, nb = 0, ncu = 0;
        hipDeviceGetAttribute(&coop, hipDeviceAttributeCooperativeLaunch, 0);
        hipOccupancyMaxActiveBlocksPerMultiprocessor(&nb, k_fused, 256, 0);
        hipDeviceGetAttribute(&ncu, hipDeviceAttributeMultiprocessorCount, 0);
        coop_ok = (coop && (long)nb * ncu >= NBLK) ? 1 : 0;
    }

    if (coop_ok && ws_size >= need) {
        const float4* lg4 = (const float4*)logits;
        const float4* wt4 = (const float4*)weight;
        const float4* bs4 = (const float4*)baselines;
        const float4* lp4 = (const float4*)log_probs;
        float4*       cm4 = (float4*)cum;
        float4*       pt4 = (float4*)partials;
        void* args[] = {(void*)&lg4, (void*)&wt4, (void*)&bs4, (void*)&lp4,
                        (void*)&obj, (void*)&cm4, (void*)&pt4, (void*)&colsum};
        hipError_t rc = hipLaunchCooperativeKernel((const void*)k_fused,
                                                   dim3(NBLK), dim3(256),
                                                   args, 0, stream);
        if (rc == hipSuccess) return;
    }

    // R1-verified fallback
    k_zero  <<<T_DIM / 256, 256, 0, stream>>>(colsum);
    k_scan  <<<B_DIM, 256, 0, stream>>>((const float4*)logits, (const float4*)weight,
                                        (float4*)cum);
    k_colsum<<<dim3(T_DIM / 256, 128), 256, 0, stream>>>(cum, baselines, colsum);
    k_obj   <<<B_DIM, 256, 0, stream>>>((const float4*)cum, (const float4*)baselines,
                                        (const float4*)log_probs, (const float4*)colsum, obj);
}